// Round 2
// baseline (5456.953 us; speedup 1.0000x reference)
//
#include <hip/hip_runtime.h>
#include <hip/hip_bf16.h>
#include <stdint.h>

// ---------------------------------------------------------------------------
// CustomConvLayer: out[b,o,h,w] = sum_{c,dh,dw} xpad[b,c,h+dh,w+dw] * W[o,c,dh*3+dw]
// Implicit-im2col GEMM, bf16 MFMA 16x16x32. M=B*H*W, N=128, K=576.
//
// R2 structure: per block (b,h) the 3 needed xpad rows form ONE contiguous
// 49.9 KB slab -> staged to LDS once (global_load_lds, source-side XOR
// swizzle), K-loop has NO barriers. B is prepacked into MFMA-fragment order
// (BtF, 147 KB, L2-resident) and loaded straight to VGPRs, coalesced.
// ---------------------------------------------------------------------------

typedef __bf16 bf16x8 __attribute__((ext_vector_type(8)));
typedef float  f32x4  __attribute__((ext_vector_type(4)));

#define GLD_TO_LDS16(g, l)                                                        \
  __builtin_amdgcn_global_load_lds((const __attribute__((address_space(1))) void*)(g), \
                                   (__attribute__((address_space(3))) void*)(l), 16, 0, 0)

// ---------------- x NCHW fp32 -> padded NHWC bf16 (interior only) ------------
__global__ __launch_bounds__(256) void xform_x(const float* __restrict__ x,
                                               __bf16* __restrict__ xpad) {
  __shared__ float tile[64][129];  // +1 pad: write phase reads column-wise
  const int tid = threadIdx.x;
  const int b = blockIdx.x >> 7;
  const int h = blockIdx.x & 127;
  const float* src = x + (((size_t)b * 64) * 128 + h) * 128;  // + c*128*128 + w
  for (int i = tid; i < 2048; i += 256) {            // 2048 float4 reads
    const int c = i >> 5, w4 = i & 31;
    f32x4 v = *(const f32x4*)(src + (size_t)c * 16384 + w4 * 4);
    tile[c][w4 * 4 + 0] = v[0];
    tile[c][w4 * 4 + 1] = v[1];
    tile[c][w4 * 4 + 2] = v[2];
    tile[c][w4 * 4 + 3] = v[3];
  }
  __syncthreads();
  __bf16* dst = xpad + ((size_t)(b * 130 + h + 1) * 130 + 1) * 64;
  for (int i = tid; i < 1024; i += 256) {            // 1024 bf16x8 stores
    const int w = i >> 3, cg = i & 7;
    bf16x8 o;
#pragma unroll
    for (int r = 0; r < 8; ++r) o[r] = (__bf16)tile[cg * 8 + r][w];
    *(bf16x8*)(dst + (size_t)w * 64 + cg * 8) = o;
  }
}

// ---------------- zero only the 1-px border of xpad (replaces 34.6MB memset) -
__global__ __launch_bounds__(256) void zero_border(__bf16* __restrict__ xpad) {
  const int idx = blockIdx.x * 256 + threadIdx.x;
  if (idx >= 16 * 33024) return;
  const int b = idx / 33024;
  const int rem = idx % 33024;
  const size_t base = (size_t)b * 130 * 130 * 64;
  size_t off;
  if (rem < 16640) {                      // rows hp=0 and hp=129 (130*64 each)
    const int r = rem / 8320, e = rem % 8320;
    off = (size_t)(r ? 129 : 0) * 8320 + e;
  } else {                                // cols wp=0,129 for hp=1..128
    const int rem2 = rem - 16640;
    const int side = rem2 >> 13, e = rem2 & 8191;
    const int h1 = (e >> 6) + 1, c = e & 63;
    off = (size_t)h1 * 8320 + (side ? 129 : 0) * 64 + c;
  }
  xpad[base + off] = (__bf16)0.f;
}

// ---------------- weights -> fragment-order BtF[s][quad][n] 16B chunks -------
// chunk(s,quad,n)[r] = W[n][c][tap] with k = s*32+quad*8+r, tap=k>>6, c=k&63
__global__ __launch_bounds__(256) void xform_w(const float* __restrict__ wgt,
                                               __bf16* __restrict__ BtF) {
  const int t = blockIdx.x * 256 + threadIdx.x;  // chunk id
  if (t >= 9216) return;
  const int s = t >> 9, rem = t & 511, quad = rem >> 7, n = rem & 127;
  bf16x8 o;
#pragma unroll
  for (int r = 0; r < 8; ++r) {
    const int k = s * 32 + quad * 8 + r;
    const int tap = k >> 6, c = k & 63;
    o[r] = (__bf16)wgt[(n * 64 + c) * 9 + tap];
  }
  *(bf16x8*)(BtF + (size_t)t * 8) = o;
}

// ---------------- main GEMM: block=(b,h), A slab resident, no K-loop barriers
__global__ __launch_bounds__(256) void conv_mfma(const __bf16* __restrict__ xpad,
                                                 const __bf16* __restrict__ BtF,
                                                 float* __restrict__ out) {
  __shared__ alignas(16) __bf16 Aslab[3120 * 8];  // 49,920 B: 3 rows x 130 w x 64 c
  const int tid  = threadIdx.x;
  const int lane = tid & 63;
  const int wave = tid >> 6;
  const int quad = lane >> 4;
  const int l16  = lane & 15;
  // XCD-aware swizzle: same-XCD blocks get contiguous (b,h) -> slab-row L2 reuse
  const int rank = (blockIdx.x & 7) * 256 + (blockIdx.x >> 3);
  const int b = rank >> 7;
  const int h = rank & 127;
  const int wm = wave >> 1;  // M half
  const int wn = wave & 1;   // N half

  // ---- stage the contiguous 3-row slab once, XOR swizzle folded into source
  // LDS slot l holds source chunk (l&~7) | ((l&7) ^ ((l>>3)&7));  v=w-pos, 8 chunks/v
  const __bf16* slab = xpad + ((size_t)(b * 130 + h) * 130) * 64;
#pragma unroll
  for (int it = 0; it < 13; ++it) {
    const int l = tid + it * 256;
    if (l < 3120) {
      const int v = l >> 3;
      const int cqs = (l & 7) ^ (v & 7);
      char* la = (char*)Aslab + ((it * 256 + wave * 64) << 4);  // wave-uniform base
      GLD_TO_LDS16(slab + v * 64 + cqs * 8, la);
    }
  }
  __syncthreads();  // the only barrier

  f32x4 acc[4][4] = {};
  bf16x8 aF[2][4], bF[2][4];

  auto load_frags = [&](int s, bf16x8* aT, bf16x8* bT) {
    const int tap = s >> 1;
    const int dh = tap / 3, dw = tap % 3;
    const int cq = ((s & 1) << 2) + quad;  // 16B chunk index within a 64-elem row
#pragma unroll
    for (int i = 0; i < 4; ++i) {
      const int m = (wm << 6) + (i << 4) + l16;
      const int v = dh * 130 + m + dw;
      const int slot = (v << 3) + (cq ^ (v & 7));
      aT[i] = *(const bf16x8*)(Aslab + (size_t)slot * 8);
      const int n = (wn << 6) + (i << 4) + l16;
      bT[i] = *(const bf16x8*)(BtF + ((size_t)((s * 4 + quad) * 128 + n) << 3));
    }
  };

  load_frags(0, aF[0], bF[0]);
#pragma unroll 2
  for (int s = 0; s < 18; ++s) {
    const int cur = s & 1, nxt = cur ^ 1;
    if (s < 17) load_frags(s + 1, aF[nxt], bF[nxt]);
#pragma unroll
    for (int i = 0; i < 4; ++i)
#pragma unroll
      for (int j = 0; j < 4; ++j)
        acc[i][j] = __builtin_amdgcn_mfma_f32_16x16x32_bf16(aF[cur][i], bF[cur][j],
                                                            acc[i][j], 0, 0, 0);
  }

  // epilogue: D col = lane&15 = n, row = quad*4+reg = m (out w)
#pragma unroll
  for (int j = 0; j < 4; ++j) {
    const int n = (wn << 6) + (j << 4) + l16;
    float* orow = out + (((size_t)(b * 128 + n) * 128 + h) << 7);
#pragma unroll
    for (int i = 0; i < 4; ++i) {
      const int m0 = (wm << 6) + (i << 4) + (quad << 2);
      *(f32x4*)(orow + m0) = acc[i][j];  // quads 0..3 tile one 64B line per n
    }
  }
}

// ---------------- fallback (if workspace too small): direct fp32 conv -------
__global__ void conv_naive(const float* __restrict__ x, const float* __restrict__ wgt,
                           float* __restrict__ out, int total) {
  int idx = blockIdx.x * 256 + threadIdx.x;
  if (idx >= total) return;
  const int w = idx & 127;
  const int h = (idx >> 7) & 127;
  const int o = (idx >> 14) & 127;
  const int b = idx >> 21;
  float s = 0.f;
  for (int c = 0; c < 64; ++c) {
    const float* xc = x + ((size_t)(b * 64 + c) * 128) * 128;
    const float* wc = wgt + (o * 64 + c) * 9;
    for (int dh = 0; dh < 3; ++dh) {
      const int hh = h + dh - 1;
      if (hh < 0 || hh >= 128) continue;
      for (int dw = 0; dw < 3; ++dw) {
        const int ww = w + dw - 1;
        if (ww < 0 || ww >= 128) continue;
        s += xc[hh * 128 + ww] * wc[dh * 3 + dw];
      }
    }
  }
  out[idx] = s;
}

extern "C" void kernel_launch(void* const* d_in, const int* in_sizes, int n_in,
                              void* d_out, int out_size, void* d_ws, size_t ws_size,
                              hipStream_t stream) {
  const float* x   = (const float*)d_in[0];
  const float* wgt = (const float*)d_in[1];
  float* out = (float*)d_out;

  const size_t BTF_BYTES  = 9216ull * 16;                             // 147456
  const size_t XPAD_BYTES = 16ull * 130 * 130 * 64 * sizeof(__bf16);  // 34.6 MB

  if (ws_size < BTF_BYTES + XPAD_BYTES) {
    const int total = 16 * 128 * 128 * 128;
    conv_naive<<<(total + 255) / 256, 256, 0, stream>>>(x, wgt, out, total);
    return;
  }

  __bf16* BtF  = (__bf16*)d_ws;
  __bf16* xpad = (__bf16*)((char*)d_ws + BTF_BYTES);

  zero_border<<<(16 * 33024 + 255) / 256, 256, 0, stream>>>(xpad);
  xform_w<<<(9216 + 255) / 256, 256, 0, stream>>>(wgt, BtF);
  xform_x<<<16 * 128, 256, 0, stream>>>(x, xpad);
  conv_mfma<<<16 * 128, 256, 0, stream>>>(xpad, BtF, out);
}

// Round 3
// 220.943 us; speedup vs baseline: 24.6985x; 24.6985x over previous
//
#include <hip/hip_runtime.h>
#include <hip/hip_bf16.h>
#include <stdint.h>

// ---------------------------------------------------------------------------
// CustomConvLayer: out[b,o,h,w] = sum_{c,dh,dw} xpad[b,c,h+dh,w+dw] * W[o,c,dh*3+dw]
// Implicit-im2col GEMM, bf16 MFMA 16x16x32. M=B*H*W, N=128, K=576.
//
// Structure: per block (b,h) the 3 needed xpad rows form ONE contiguous
// 49.9 KB slab -> staged to LDS once (global_load_lds width=16, source-side
// XOR swizzle), then a fully-unrolled K-loop with NO barriers. B is prepacked
// in MFMA-fragment order (BtF, 147 KB, L2-resident) -> coalesced global loads
// straight to VGPRs. R3: all fragment arrays are plain constant-indexed
// locals (R2's lambda/pointer indirection demoted them to scratch -> 70x).
// ---------------------------------------------------------------------------

typedef __bf16 bf16x8 __attribute__((ext_vector_type(8)));
typedef float  f32x4  __attribute__((ext_vector_type(4)));

#define GLD_TO_LDS16(g, l)                                                        \
  __builtin_amdgcn_global_load_lds((const __attribute__((address_space(1))) void*)(g), \
                                   (__attribute__((address_space(3))) void*)(l), 16, 0, 0)

// ---------------- x NCHW fp32 -> padded NHWC bf16 (interior only) ------------
__global__ __launch_bounds__(256) void xform_x(const float* __restrict__ x,
                                               __bf16* __restrict__ xpad) {
  __shared__ float tile[64][129];  // +1 pad: write phase reads column-wise
  const int tid = threadIdx.x;
  const int b = blockIdx.x >> 7;
  const int h = blockIdx.x & 127;
  const float* src = x + (((size_t)b * 64) * 128 + h) * 128;  // + c*128*128 + w
  for (int i = tid; i < 2048; i += 256) {            // 2048 float4 reads
    const int c = i >> 5, w4 = i & 31;
    f32x4 v = *(const f32x4*)(src + (size_t)c * 16384 + w4 * 4);
    tile[c][w4 * 4 + 0] = v[0];
    tile[c][w4 * 4 + 1] = v[1];
    tile[c][w4 * 4 + 2] = v[2];
    tile[c][w4 * 4 + 3] = v[3];
  }
  __syncthreads();
  __bf16* dst = xpad + ((size_t)(b * 130 + h + 1) * 130 + 1) * 64;
  for (int i = tid; i < 1024; i += 256) {            // 1024 bf16x8 stores
    const int w = i >> 3, cg = i & 7;
    bf16x8 o;
#pragma unroll
    for (int r = 0; r < 8; ++r) o[r] = (__bf16)tile[cg * 8 + r][w];
    *(bf16x8*)(dst + (size_t)w * 64 + cg * 8) = o;
  }
}

// ---------------- zero only the 1-px border of xpad (replaces 34.6MB memset) -
__global__ __launch_bounds__(256) void zero_border(__bf16* __restrict__ xpad) {
  const int idx = blockIdx.x * 256 + threadIdx.x;
  if (idx >= 16 * 33024) return;
  const int b = idx / 33024;
  const int rem = idx % 33024;
  const size_t base = (size_t)b * 130 * 130 * 64;
  size_t off;
  if (rem < 16640) {                      // rows hp=0 and hp=129 (130*64 each)
    const int r = rem / 8320, e = rem % 8320;
    off = (size_t)(r ? 129 : 0) * 8320 + e;
  } else {                                // cols wp=0,129 for hp=1..128
    const int rem2 = rem - 16640;
    const int side = rem2 >> 13, e = rem2 & 8191;
    const int h1 = (e >> 6) + 1, c = e & 63;
    off = (size_t)h1 * 8320 + (side ? 129 : 0) * 64 + c;
  }
  xpad[base + off] = (__bf16)0.f;
}

// ---------------- weights -> fragment-order BtF[s][quad][n] 16B chunks -------
// chunk(s,quad,n)[r] = W[n][c][tap] with k = s*32+quad*8+r, tap=k>>6, c=k&63
__global__ __launch_bounds__(256) void xform_w(const float* __restrict__ wgt,
                                               __bf16* __restrict__ BtF) {
  const int t = blockIdx.x * 256 + threadIdx.x;  // chunk id
  if (t >= 9216) return;
  const int s = t >> 9, rem = t & 511, quad = rem >> 7, n = rem & 127;
  bf16x8 o;
#pragma unroll
  for (int r = 0; r < 8; ++r) {
    const int k = s * 32 + quad * 8 + r;
    const int tap = k >> 6, c = k & 63;
    o[r] = (__bf16)wgt[(n * 64 + c) * 9 + tap];
  }
  *(bf16x8*)(BtF + (size_t)t * 8) = o;
}

// ---------------- main GEMM: block=(b,h), A slab resident, no K-loop barriers
__global__ __launch_bounds__(256) void conv_mfma(const __bf16* __restrict__ xpad,
                                                 const __bf16* __restrict__ BtF,
                                                 float* __restrict__ out) {
  __shared__ alignas(16) __bf16 Aslab[3120 * 8];  // 49,920 B: 3 rows x 130 w x 64 c
  const int tid  = threadIdx.x;
  const int lane = tid & 63;
  const int wave = tid >> 6;
  const int quad = lane >> 4;
  const int l16  = lane & 15;
  // XCD-aware swizzle: same-XCD blocks get contiguous (b,h) -> slab-row L2 reuse
  const int rank = (blockIdx.x & 7) * 256 + (blockIdx.x >> 3);
  const int b = rank >> 7;
  const int h = rank & 127;
  const int wm = wave >> 1;  // M half
  const int wn = wave & 1;   // N half

  // ---- stage the contiguous 3-row slab once, XOR swizzle folded into source
  // LDS slot l holds source chunk (l&~7) | ((l&7) ^ ((l>>3)&7));  v=w-pos, 8 chunks/v
  const __bf16* slab = xpad + ((size_t)(b * 130 + h) * 130) * 64;
#pragma unroll
  for (int it = 0; it < 13; ++it) {
    const int l = tid + it * 256;
    if (l < 3120) {
      const int v = l >> 3;
      const int cqs = (l & 7) ^ (v & 7);
      char* la = (char*)Aslab + ((it * 256 + wave * 64) << 4);  // wave-uniform base
      GLD_TO_LDS16(slab + v * 64 + cqs * 8, la);
    }
  }
  __syncthreads();  // the only barrier

  f32x4 acc[4][4] = {};

#pragma unroll
  for (int s = 0; s < 18; ++s) {
    const int tap = s >> 1;
    const int dh = tap / 3, dw = tap % 3;
    const int cq = ((s & 1) << 2) + quad;  // 16B chunk index within a 64-elem row
    bf16x8 aF[4], bF[4];                   // plain locals, constant-indexed (SROA)
#pragma unroll
    for (int i = 0; i < 4; ++i) {
      const int m = (wm << 6) + (i << 4) + l16;
      const int v = dh * 130 + m + dw;
      const int slot = (v << 3) + (cq ^ (v & 7));
      aF[i] = *(const bf16x8*)(Aslab + (size_t)slot * 8);
      const int n = (wn << 6) + (i << 4) + l16;
      bF[i] = *(const bf16x8*)(BtF + ((size_t)((s * 4 + quad) * 128 + n) << 3));
    }
#pragma unroll
    for (int i = 0; i < 4; ++i)
#pragma unroll
      for (int j = 0; j < 4; ++j)
        acc[i][j] = __builtin_amdgcn_mfma_f32_16x16x32_bf16(aF[i], bF[j], acc[i][j], 0, 0, 0);
  }

  // epilogue: D col = lane&15 = n, row = quad*4+reg = m (out w)
#pragma unroll
  for (int j = 0; j < 4; ++j) {
    const int n = (wn << 6) + (j << 4) + l16;
    float* orow = out + (((size_t)(b * 128 + n) * 128 + h) << 7);
#pragma unroll
    for (int i = 0; i < 4; ++i) {
      const int m0 = (wm << 6) + (i << 4) + (quad << 2);
      *(f32x4*)(orow + m0) = acc[i][j];  // quads 0..3 tile one 64B line per n
    }
  }
}

// ---------------- fallback (if workspace too small): direct fp32 conv -------
__global__ void conv_naive(const float* __restrict__ x, const float* __restrict__ wgt,
                           float* __restrict__ out, int total) {
  int idx = blockIdx.x * 256 + threadIdx.x;
  if (idx >= total) return;
  const int w = idx & 127;
  const int h = (idx >> 7) & 127;
  const int o = (idx >> 14) & 127;
  const int b = idx >> 21;
  float s = 0.f;
  for (int c = 0; c < 64; ++c) {
    const float* xc = x + ((size_t)(b * 64 + c) * 128) * 128;
    const float* wc = wgt + (o * 64 + c) * 9;
    for (int dh = 0; dh < 3; ++dh) {
      const int hh = h + dh - 1;
      if (hh < 0 || hh >= 128) continue;
      for (int dw = 0; dw < 3; ++dw) {
        const int ww = w + dw - 1;
        if (ww < 0 || ww >= 128) continue;
        s += xc[hh * 128 + ww] * wc[dh * 3 + dw];
      }
    }
  }
  out[idx] = s;
}

extern "C" void kernel_launch(void* const* d_in, const int* in_sizes, int n_in,
                              void* d_out, int out_size, void* d_ws, size_t ws_size,
                              hipStream_t stream) {
  const float* x   = (const float*)d_in[0];
  const float* wgt = (const float*)d_in[1];
  float* out = (float*)d_out;

  const size_t BTF_BYTES  = 9216ull * 16;                             // 147456
  const size_t XPAD_BYTES = 16ull * 130 * 130 * 64 * sizeof(__bf16);  // 34.6 MB

  if (ws_size < BTF_BYTES + XPAD_BYTES) {
    const int total = 16 * 128 * 128 * 128;
    conv_naive<<<(total + 255) / 256, 256, 0, stream>>>(x, wgt, out, total);
    return;
  }

  __bf16* BtF  = (__bf16*)d_ws;
  __bf16* xpad = (__bf16*)((char*)d_ws + BTF_BYTES);

  zero_border<<<(16 * 33024 + 255) / 256, 256, 0, stream>>>(xpad);
  xform_w<<<(9216 + 255) / 256, 256, 0, stream>>>(wgt, BtF);
  xform_x<<<16 * 128, 256, 0, stream>>>(x, xpad);
  conv_mfma<<<16 * 128, 256, 0, stream>>>(xpad, BtF, out);
}